// Round 5
// baseline (580.793 us; speedup 1.0000x reference)
//
#include <hip/hip_runtime.h>
#include <stdint.h>

typedef __bf16 bf16;
typedef __bf16 bf16x8 __attribute__((ext_vector_type(8)));
typedef float floatx4 __attribute__((ext_vector_type(4)));

#define HH     16
#define DNOPE  128
#define DROPE  64
#define DV     128
#define DQK    192
#define HID    2048
#define QLR    1536
#define KVLR   512
#define BB     4
#define SS     1024
#define NTOK   4096
#define XOUTW  2176
#define EPSF   1e-6f

// ---------------- helpers ----------------
__device__ inline void cvt_store4(bf16* dst, float a, float b, float c, float d) {
  union { bf16 h[4]; uint2 u; } t;
  t.h[0] = (bf16)a; t.h[1] = (bf16)b; t.h[2] = (bf16)c; t.h[3] = (bf16)d;
  *(uint2*)dst = t.u;
}

__device__ inline void gl_lds16(const bf16* g, bf16* l) {
  __builtin_amdgcn_global_load_lds(
      (const __attribute__((address_space(1))) void*)g,
      (__attribute__((address_space(3))) void*)l, 16, 0, 0);
}

// ---------------- merged fp32 -> bf16 conversion (all weights + x) --------
// block ranges: [0,8192) x | [8192,11264) wq_a | [11264,12544) wkv_a pad |
// [12544,17152) wq_b*SCALEQ | [17152,18176) wk_b | [18176,19200) wv_b |
// [19200,23296) wo
__global__ __launch_bounds__(256) void cvt_all(
    const float* __restrict__ x, const float* __restrict__ wq_a,
    const float* __restrict__ wkv_a, const float* __restrict__ wq_b,
    const float* __restrict__ wk_b, const float* __restrict__ wv_b,
    const float* __restrict__ wo, bf16* __restrict__ xb,
    bf16* __restrict__ wA, bf16* __restrict__ wqbb,
    bf16* __restrict__ wkvB, bf16* __restrict__ wob, float scaleq) {
  const int blk = blockIdx.x, tid = threadIdx.x;
  const float* s; bf16* d; int rel; float sc = 1.0f;
  if (blk < 8192)       { rel = blk;         s = x;    d = xb; }
  else if (blk < 11264) { rel = blk - 8192;  s = wq_a; d = wA; }
  else if (blk < 12544) { // wkv_a pad to 640 rows
    rel = blk - 11264;
    int i = (rel * 256 + tid) << 2;
    bf16* dd = wA + 3145728;
    if ((i >> 11) < 576) {
      float4 v = *(const float4*)(wkv_a + i);
      cvt_store4(dd + i, v.x, v.y, v.z, v.w);
    } else {
      *(uint2*)(dd + i) = make_uint2(0u, 0u);
    }
    return;
  }
  else if (blk < 17152) { rel = blk - 12544; s = wq_b; d = wqbb; sc = scaleq; }
  else if (blk < 18176) { rel = blk - 17152; s = wk_b; d = wkvB; }
  else if (blk < 19200) { rel = blk - 18176; s = wv_b; d = wkvB + 1048576; }
  else                  { rel = blk - 19200; s = wo;   d = wob; }
  int i = (rel * 256 + tid) << 2;
  float4 v = *(const float4*)(s + i);
  cvt_store4(d + i, v.x * sc, v.y * sc, v.z * sc, v.w * sc);
}

// ---------------- GEMM: C[M,N] = A[M,K] @ Bw[N,K]^T (all bf16 in) ----------
template <typename TC, int EPI>
__global__ __launch_bounds__(256) void gemm_bt_bf16(
    const bf16* __restrict__ A, const bf16* __restrict__ Bw,
    TC* __restrict__ C0, bf16* __restrict__ C1, int M, int N, int K) {
  __shared__ __align__(16) bf16 As[128 * 64];
  __shared__ __align__(16) bf16 Bs[128 * 64];
  const int tid  = threadIdx.x;
  const int wave = tid >> 6, lane = tid & 63;
  const int m0 = blockIdx.x << 7, n0 = blockIdx.y << 7;
  const int quad = lane >> 4, l16 = lane & 15;
  const int wm = (wave >> 1) << 6, wn = (wave & 1) << 6;
  const int srow = wave << 5;
  const int lrow = lane >> 3;
  const int lcol = (lane & 7) << 3;

  const bf16* gA = A  + (size_t)(m0 + srow + lrow) * K + lcol;
  const bf16* gB = Bw + (size_t)(n0 + srow + lrow) * K + lcol;
  bf16* lA = As + srow * 64;
  bf16* lB = Bs + srow * 64;

  floatx4 acc[4][4];
#pragma unroll
  for (int i = 0; i < 4; i++)
#pragma unroll
    for (int j = 0; j < 4; j++) acc[i][j] = floatx4{0.f, 0.f, 0.f, 0.f};

  for (int k0 = 0; k0 < K; k0 += 64) {
    __syncthreads();
#pragma unroll
    for (int t = 0; t < 4; t++) {
      gl_lds16(gA + (size_t)(t << 3) * K + k0, lA + (t << 3) * 64);
      gl_lds16(gB + (size_t)(t << 3) * K + k0, lB + (t << 3) * 64);
    }
    __syncthreads();
#pragma unroll
    for (int ks = 0; ks < 2; ks++) {
      bf16x8 af[4], bv[4];
#pragma unroll
      for (int i = 0; i < 4; i++)
        af[i] = *(const bf16x8*)&As[(wm + (i << 4) + l16) * 64 + (ks << 5) + (quad << 3)];
#pragma unroll
      for (int j = 0; j < 4; j++)
        bv[j] = *(const bf16x8*)&Bs[(wn + (j << 4) + l16) * 64 + (ks << 5) + (quad << 3)];
#pragma unroll
      for (int i = 0; i < 4; i++)
#pragma unroll
        for (int j = 0; j < 4; j++)
          acc[i][j] = __builtin_amdgcn_mfma_f32_16x16x32_bf16(af[i], bv[j], acc[i][j], 0, 0, 0);
    }
  }

  if constexpr (EPI == 1) {
    if (n0 >= 2048) {
#pragma unroll
      for (int i = 0; i < 4; i++) {
        int gm = m0 + wm + (i << 4) + (quad << 2);
        int bb = gm >> 10, s = gm & 1023;
#pragma unroll
        for (int j = 0; j < 4; j++) {
          int gn = n0 + wn + (j << 4) + l16 - 2048;
          int hh = gn >> 7, vd = gn & 127;
          union { bf16 h4[4]; uint2 u; } pk;
#pragma unroll
          for (int r = 0; r < 4; r++) pk.h4[r] = (bf16)acc[i][j][r];
          *(uint2*)(C1 + ((((size_t)bb * HH + hh) * DV + vd) << 10) + s) = pk.u;
        }
      }
      return;
    }
  }
  const int ldc = (EPI == 1) ? 2048 : N;
#pragma unroll
  for (int i = 0; i < 4; i++)
#pragma unroll
    for (int j = 0; j < 4; j++) {
      int gn = n0 + wn + (j << 4) + l16;
#pragma unroll
      for (int r = 0; r < 4; r++) {
        int gm = m0 + wm + (i << 4) + (quad << 2) + r;
        C0[(size_t)gm * ldc + gn] = (TC)acc[i][j][r];
      }
    }
}

// ---------------- fused rmsnorm(q) + rmsnorm(kv) + rope_k ----------------
// blocks [0,4096): rms q row | [4096,8192): rms kv row | [8192,8704): rope_k
__global__ __launch_bounds__(256) void norm_rope(
    const bf16* __restrict__ xout, const float* __restrict__ w_qa_ln,
    const float* __restrict__ w_kva_ln, bf16* __restrict__ qln,
    bf16* __restrict__ ckv, bf16* __restrict__ kpe,
    const float* __restrict__ rsin, const float* __restrict__ rcos) {
  const int blk = blockIdx.x, tid = threadIdx.x;
  if (blk < 8192) {
    const int row = blk & 4095;
    const bool isq = blk < 4096;
    const bf16* p = xout + (size_t)row * XOUTW + (isq ? 0 : QLR);
    const float* w = isq ? w_qa_ln : w_kva_ln;
    bf16* o = isq ? (qln + (size_t)row * QLR) : (ckv + (size_t)row * KVLR);
    const int L = isq ? QLR : KVLR;
    float ss = 0.f;
    for (int c = tid << 2; c < L; c += 1024) {
      union { uint2 u; bf16 h[4]; } t;
      t.u = *(const uint2*)(p + c);
#pragma unroll
      for (int r = 0; r < 4; r++) { float v = (float)t.h[r]; ss += v * v; }
    }
#pragma unroll
    for (int off = 32; off > 0; off >>= 1) ss += __shfl_down(ss, off);
    __shared__ float red[4];
    if ((tid & 63) == 0) red[tid >> 6] = ss;
    __syncthreads();
    float rs = rsqrtf((red[0] + red[1] + red[2] + red[3]) / (float)L + EPSF);
    for (int c = tid << 2; c < L; c += 1024) {
      union { uint2 u; bf16 h[4]; } t, ot;
      t.u = *(const uint2*)(p + c);
#pragma unroll
      for (int r = 0; r < 4; r++) ot.h[r] = (bf16)((float)t.h[r] * rs * w[c + r]);
      *(uint2*)(o + c) = ot.u;
    }
  } else {
    int idx = (blk - 8192) * 256 + tid;   // NTOK*32
    int i = idx & 31, row = idx >> 5;
    int pos = row & (SS - 1);
    union { uint u; bf16 h2[2]; } t;
    t.u = *(const uint*)(xout + (size_t)row * XOUTW + QLR + KVLR + (i << 1));
    float e = (float)t.h2[0], o = (float)t.h2[1];
    float c = rcos[(pos << 5) + i], s = rsin[(pos << 5) + i];
    t.h2[0] = (bf16)(e * c - o * s);
    t.h2[1] = (bf16)(e * s + o * c);
    *(uint*)(kpe + (size_t)row * DROPE + (i << 1)) = t.u;
  }
}

// ---------------- rope q (interleaved, bf16, in place) ----------------
__global__ void rope_q(bf16* __restrict__ q, const float* __restrict__ sin_t,
                       const float* __restrict__ cos_t) {
  int idx = blockIdx.x * 256 + threadIdx.x;   // NTOK*HH*32
  int i = idx & 31, h = (idx >> 5) & 15, row = idx >> 9;
  int pos = row & (SS - 1);
  bf16* base = q + ((size_t)row * HH + h) * DQK + DNOPE + (i << 1);
  union { uint u; bf16 h2[2]; } t;
  t.u = *(uint*)base;
  float e = (float)t.h2[0], o = (float)t.h2[1];
  float c = cos_t[(pos << 5) + i], s = sin_t[(pos << 5) + i];
  t.h2[0] = (bf16)(e * c - o * s);
  t.h2[1] = (bf16)(e * s + o * c);
  *(uint*)base = t.u;
}

// ---------------- flash attention (joint heavy+light pair) ----------------
// grid (4, H, B): block bx pairs q-tiles qtA=7-bx (heavy) and qtB=bx (light),
// 128 rows each. K/V LDS staging shared: per key slot s (64 keys), compute
// tile A always; tile B while s < nktB (its range is a subset of A's).
// 512 thr = 8 waves; wave w owns q rows [w*16,w*16+16) of BOTH tiles.
// Depth-2 register prefetch of K/V, pinned with sched_barrier.

__device__ __forceinline__ void attn_tile_step(
    const bf16x8* aq, int q0, int s, bool diag,
    bf16 (*Ks)[200], bf16 (*Vts)[72], bf16 (*Psw)[72], float* alphaSw,
    floatx4* acc_o, float* m_i, float* l_i,
    int wave, int quad, int l16) {
  const int k0 = s << 6;
  floatx4 sacc[4];
#pragma unroll
  for (int kn = 0; kn < 4; kn++) {
    floatx4 sc = floatx4{0.f, 0.f, 0.f, 0.f};
#pragma unroll
    for (int t = 0; t < 6; t++) {
      bf16x8 bk = *(const bf16x8*)&Ks[(kn << 4) + l16][(t << 5) + (quad << 3)];
      sc = __builtin_amdgcn_mfma_f32_16x16x32_bf16(aq[t], bk, sc, 0, 0, 0);
    }
    sacc[kn] = sc;
  }
  float pvv[4][4], mtile[4];
#pragma unroll
  for (int r = 0; r < 4; r++) mtile[r] = -1e30f;
  if (diag) {
#pragma unroll
    for (int kn = 0; kn < 4; kn++)
#pragma unroll
      for (int r = 0; r < 4; r++) {
        int qg = q0 + (wave << 4) + (quad << 2) + r;
        int kg = k0 + (kn << 4) + l16;
        float sv = sacc[kn][r];
        if (kg > qg) sv = -1e30f;
        pvv[kn][r] = sv;
        mtile[r] = fmaxf(mtile[r], sv);
      }
  } else {
#pragma unroll
    for (int kn = 0; kn < 4; kn++)
#pragma unroll
      for (int r = 0; r < 4; r++) {
        float sv = sacc[kn][r];
        pvv[kn][r] = sv;
        mtile[r] = fmaxf(mtile[r], sv);
      }
  }
  float alpha[4];
#pragma unroll
  for (int r = 0; r < 4; r++) {
#pragma unroll
    for (int off = 1; off < 16; off <<= 1)
      mtile[r] = fmaxf(mtile[r], __shfl_xor(mtile[r], off));
    float mnew = fmaxf(m_i[r], mtile[r]);
    alpha[r] = exp2f(m_i[r] - mnew);
    m_i[r] = mnew;
    float part = 0.f;
#pragma unroll
    for (int kn = 0; kn < 4; kn++) {
      float p = exp2f(pvv[kn][r] - mnew);
      pvv[kn][r] = p;
      part += p;
    }
#pragma unroll
    for (int off = 1; off < 16; off <<= 1) part += __shfl_xor(part, off);
    l_i[r] = l_i[r] * alpha[r] + part;
  }
#pragma unroll
  for (int kn = 0; kn < 4; kn++)
#pragma unroll
    for (int r = 0; r < 4; r++)
      Psw[(quad << 2) + r][(kn << 4) + l16] = (bf16)pvv[kn][r];
  if (l16 == 0)
    *(float4*)&alphaSw[quad << 2] =
        make_float4(alpha[0], alpha[1], alpha[2], alpha[3]);
  float alpha_lane = alphaSw[l16];
#pragma unroll
  for (int n = 0; n < 8; n++)
#pragma unroll
    for (int r = 0; r < 4; r++) acc_o[n][r] *= alpha_lane;
  bf16x8 bp[2];
#pragma unroll
  for (int t = 0; t < 2; t++)
    bp[t] = *(const bf16x8*)&Psw[l16][(t << 5) + (quad << 3)];
#pragma unroll
  for (int n = 0; n < 8; n++) {
#pragma unroll
    for (int t = 0; t < 2; t++) {
      bf16x8 av = *(const bf16x8*)&Vts[(n << 4) + l16][(t << 5) + (quad << 3)];
      acc_o[n] = __builtin_amdgcn_mfma_f32_16x16x32_bf16(av, bp[t], acc_o[n], 0, 0, 0);
    }
  }
}

__device__ __forceinline__ void attn_epilogue(
    bf16* out, int b, int h, int q0, floatx4* acc_o, float* l_i,
    float* invlSw, int wave, int quad, int l16) {
  if (l16 == 0)
    *(float4*)&invlSw[quad << 2] =
        make_float4(1.f / l_i[0], 1.f / l_i[1], 1.f / l_i[2], 1.f / l_i[3]);
  float invl = invlSw[l16];
  int tok = (b << 10) + q0 + (wave << 4) + l16;
  bf16* obase = out + ((size_t)tok * HH + h) * DV + (quad << 2);
#pragma unroll
  for (int n = 0; n < 8; n++) {
    union { bf16 h4[4]; uint2 u; } pk;
#pragma unroll
    for (int r = 0; r < 4; r++) pk.h4[r] = (bf16)(acc_o[n][r] * invl);
    *(uint2*)(obase + (n << 4)) = pk.u;
  }
}

__global__ __launch_bounds__(512) void attn_kernel(
    const bf16* __restrict__ q, const bf16* __restrict__ knope,
    const bf16* __restrict__ kpe, const bf16* __restrict__ vT,
    bf16* __restrict__ out) {
  const int bx = blockIdx.x;                 // 0..3
  const int qtA = 7 - bx, qtB = bx;
  const int q0A = qtA << 7, q0B = qtB << 7;
  const int nktA = (qtA << 1) + 2;           // 16,14,12,10
  const int nktB = (qtB << 1) + 2;           // 2,4,6,8  (subset of A's range)
  const int h = blockIdx.y, b = blockIdx.z;
  __shared__ __align__(16) bf16 Ks[64][200];
  __shared__ __align__(16) bf16 Vts[128][72];
  __shared__ __align__(16) bf16 PsA[8][16][72];
  __shared__ __align__(16) bf16 PsB[8][16][72];
  __shared__ float alphaSA[8][16], alphaSB[8][16], invlS[8][16];
  const int tid = threadIdx.x, wave = tid >> 6, lane = tid & 63;
  const int quad = lane >> 4, l16 = lane & 15;

  // staging coords
  const int knr = tid >> 4, knc = (tid & 15) << 3;
  const int kpr = tid >> 3, kpc = (tid & 7) << 3;
  const int vtr = tid >> 3, vtc = (tid & 7) << 3;
  const bf16* knbase = knope + ((size_t)((b << 10) + knr) * HH + h) * DNOPE + knc;
  const bf16* kpbase = kpe + (size_t)((b << 10) + kpr) * DROPE + kpc;
  const bf16* vtbase = vT + ((((size_t)b * HH + h) * DV + vtr) << 10) + vtc;

#define LOADSLOT(Pk0, Pk1, Pp, Pv0, Pv1, S)                         \
  { size_t ko = (size_t)(S) << 6;                                   \
    Pk0 = *(const uint4*)(knbase + ko * HH * DNOPE);                \
    Pk1 = *(const uint4*)(knbase + (ko + 32) * HH * DNOPE);         \
    Pp  = *(const uint4*)(kpbase + ko * DROPE);                     \
    Pv0 = *(const uint4*)(vtbase + ko);                             \
    Pv1 = *(const uint4*)(vtbase + ko + ((size_t)64 << 10)); }

  // depth-2 prefetch: P0 = slot 0, P1 = slot 1 (nktA >= 10 always)
  uint4 p0k0, p0k1, p0p, p0v0, p0v1;
  uint4 p1k0, p1k1, p1p, p1v0, p1v1;
  LOADSLOT(p0k0, p0k1, p0p, p0v0, p0v1, 0);
  LOADSLOT(p1k0, p1k1, p1p, p1v0, p1v1, 1);

  // Q fragments for both tiles: 4 staging rounds through Ks
  bf16x8 aqA[6], aqB[6];
#pragma unroll
  for (int t = 0; t < 4; t++) {
    const int tile = t >> 1, half = t & 1;
    const int q0 = tile ? q0B : q0A;
    __syncthreads();
    for (int i = tid; i < 64 * 24; i += 512) {
      int r = i / 24, c = (i % 24) << 3;
      *(uint4*)&Ks[r][c] = *(const uint4*)(
          q + ((size_t)((b << 10) + q0 + (half << 6) + r) * HH + h) * DQK + c);
    }
    __syncthreads();
    if ((wave >> 2) == half) {
      int rw = wave & 3;
      bf16x8* dst = tile ? aqB : aqA;
#pragma unroll
      for (int tt = 0; tt < 6; tt++)
        dst[tt] = *(const bf16x8*)&Ks[(rw << 4) + l16][(tt << 5) + (quad << 3)];
    }
  }

  floatx4 accA[8], accB[8];
#pragma unroll
  for (int n = 0; n < 8; n++) {
    accA[n] = floatx4{0.f, 0.f, 0.f, 0.f};
    accB[n] = floatx4{0.f, 0.f, 0.f, 0.f};
  }
  float mA[4], lA[4], mB[4], lB[4];
#pragma unroll
  for (int r = 0; r < 4; r++) { mA[r] = -1e30f; lA[r] = 0.f; mB[r] = -1e30f; lB[r] = 0.f; }

  for (int s = 0; s < nktA; s++) {
    __syncthreads();   // everyone done reading prev K/V (and Q rounds done)
    *(uint4*)&Ks[knr][knc] = p0k0;
    *(uint4*)&Ks[32 + knr][knc] = p0k1;
    *(uint4*)&Ks[kpr][DNOPE + kpc] = p0p;
    *(uint4*)&Vts[vtr][vtc] = p0v0;
    *(uint4*)&Vts[64 + vtr][vtc] = p0v1;
    p0k0 = p1k0; p0k1 = p1k1; p0p = p1p; p0v0 = p1v0; p0v1 = p1v1;
    if (s + 2 < nktA) {
      LOADSLOT(p1k0, p1k1, p1p, p1v0, p1v1, s + 2);
    }
    __builtin_amdgcn_sched_barrier(0);   // keep prefetch issued here
    __syncthreads();

    attn_tile_step(aqA, q0A, s, s >= nktA - 2, Ks, Vts, PsA[wave],
                   alphaSA[wave], accA, mA, lA, wave, quad, l16);
    if (s < nktB)
      attn_tile_step(aqB, q0B, s, s >= nktB - 2, Ks, Vts, PsB[wave],
                     alphaSB[wave], accB, mB, lB, wave, quad, l16);
  }

  attn_epilogue(out, b, h, q0A, accA, lA, invlS[wave], wave, quad, l16);
  attn_epilogue(out, b, h, q0B, accB, lB, invlS[wave], wave, quad, l16);
#undef LOADSLOT
}

// ---------------- launch ----------------
extern "C" void kernel_launch(void* const* d_in, const int* in_sizes, int n_in,
                              void* d_out, int out_size, void* d_ws, size_t ws_size,
                              hipStream_t stream) {
  (void)in_sizes; (void)n_in; (void)out_size; (void)ws_size;
  const float* x        = (const float*)d_in[0];
  const float* wq_a     = (const float*)d_in[1];
  const float* w_qa_ln  = (const float*)d_in[2];
  const float* wq_b     = (const float*)d_in[3];
  const float* wkv_a    = (const float*)d_in[4];
  const float* w_kva_ln = (const float*)d_in[5];
  const float* wk_b     = (const float*)d_in[6];
  const float* wv_b     = (const float*)d_in[7];
  const float* wo       = (const float*)d_in[8];
  const float* rsin     = (const float*)d_in[9];
  const float* rcos     = (const float*)d_in[10];
  float* out = (float*)d_out;

  // workspace (liveness-aliased), total ~112.2 MB
  char* ws = (char*)d_ws;
  bf16* xb    = (bf16*)(ws + 0);            // 16.78M, dead after xout gemm
  bf16* attnb = (bf16*)(ws + 0);            //   aliases xb
  bf16* xout  = (bf16*)(ws + 16777216);     // 17.83M [4096][2176]
  bf16* knope = (bf16*)(ws + 16777216);     //   aliases xout, stride 2048
  bf16* q     = (bf16*)(ws + 34603008);     // 25.17M
  bf16* qln   = (bf16*)(ws + 59768832);     // 12.58M, dead after q gemm
  bf16* vT    = (bf16*)(ws + 59768832);     //   aliases qln
  bf16* wA    = (bf16*)(ws + 76546048);     // 8.91M  [2176][2048]
  bf16* wqbb  = (bf16*)(ws + 85458944);     // 9.44M
  bf16* wkvB  = (bf16*)(ws + 94896128);     // 4.19M  [4096][512]
  bf16* wob   = (bf16*)(ws + 99090432);     // 8.39M
  bf16* ckv   = (bf16*)(ws + 107479040);    // 4.19M
  bf16* kpe   = (bf16*)(ws + 111673344);    // 0.52M -> end 112197632

  const float SCALEQ = (1.0f / sqrtf(192.0f)) * 1.44269504088896f;

  dim3 blk(256);
  cvt_all<<<23296, blk, 0, stream>>>(x, wq_a, wkv_a, wq_b, wk_b, wv_b, wo,
                                     xb, wA, wqbb, wkvB, wob, SCALEQ);
  // xout = xb @ [wq_a ; wkv_a]^T
  gemm_bt_bf16<bf16, 0><<<dim3(32, 17), blk, 0, stream>>>(
      xb, wA, xout, nullptr, NTOK, XOUTW, HID);
  // rmsnorm(q), rmsnorm(kv), rope_k in one dispatch
  norm_rope<<<8704, blk, 0, stream>>>(xout, w_qa_ln, w_kva_ln, qln, ckv, kpe,
                                      rsin, rcos);
  // q = qln @ wq_b^T (pre-scaled by SCALEQ)
  gemm_bt_bf16<bf16, 0><<<dim3(32, 24), blk, 0, stream>>>(
      qln, wqbb, q, nullptr, NTOK, HH * DQK, QLR);
  rope_q<<<8192, blk, 0, stream>>>(q, rsin, rcos);
  // [knope | vT] = ckv @ [wk_b ; wv_b]^T (dual epilogue)
  gemm_bt_bf16<bf16, 1><<<dim3(32, 32), blk, 0, stream>>>(
      ckv, wkvB, knope, vT, NTOK, 4096, KVLR);
  attn_kernel<<<dim3(4, HH, BB), dim3(512), 0, stream>>>(
      q, knope, kpe, vT, attnb);
  gemm_bt_bf16<float, 0><<<dim3(32, 16), blk, 0, stream>>>(
      attnb, wob, out, nullptr, NTOK, HID, HID);
}

// Round 6
// 501.854 us; speedup vs baseline: 1.1573x; 1.1573x over previous
//
#include <hip/hip_runtime.h>
#include <stdint.h>

typedef __bf16 bf16;
typedef __bf16 bf16x8 __attribute__((ext_vector_type(8)));
typedef float floatx4 __attribute__((ext_vector_type(4)));

#define HH     16
#define DNOPE  128
#define DROPE  64
#define DV     128
#define DQK    192
#define HID    2048
#define QLR    1536
#define KVLR   512
#define BB     4
#define SS     1024
#define NTOK   4096
#define XOUTW  2176
#define EPSF   1e-6f

// ---------------- helpers ----------------
__device__ inline void cvt_store4(bf16* dst, float a, float b, float c, float d) {
  union { bf16 h[4]; uint2 u; } t;
  t.h[0] = (bf16)a; t.h[1] = (bf16)b; t.h[2] = (bf16)c; t.h[3] = (bf16)d;
  *(uint2*)dst = t.u;
}

__device__ inline void gl_lds16(const bf16* g, bf16* l) {
  __builtin_amdgcn_global_load_lds(
      (const __attribute__((address_space(1))) void*)g,
      (__attribute__((address_space(3))) void*)l, 16, 0, 0);
}

// ---------------- merged fp32 -> bf16 conversion (all weights + x) --------
__global__ __launch_bounds__(256) void cvt_all(
    const float* __restrict__ x, const float* __restrict__ wq_a,
    const float* __restrict__ wkv_a, const float* __restrict__ wq_b,
    const float* __restrict__ wk_b, const float* __restrict__ wv_b,
    const float* __restrict__ wo, bf16* __restrict__ xb,
    bf16* __restrict__ wA, bf16* __restrict__ wqbb,
    bf16* __restrict__ wkvB, bf16* __restrict__ wob, float scaleq) {
  const int blk = blockIdx.x, tid = threadIdx.x;
  const float* s; bf16* d; int rel; float sc = 1.0f;
  if (blk < 8192)       { rel = blk;         s = x;    d = xb; }
  else if (blk < 11264) { rel = blk - 8192;  s = wq_a; d = wA; }
  else if (blk < 12544) { // wkv_a pad to 640 rows
    rel = blk - 11264;
    int i = (rel * 256 + tid) << 2;
    bf16* dd = wA + 3145728;
    if ((i >> 11) < 576) {
      float4 v = *(const float4*)(wkv_a + i);
      cvt_store4(dd + i, v.x, v.y, v.z, v.w);
    } else {
      *(uint2*)(dd + i) = make_uint2(0u, 0u);
    }
    return;
  }
  else if (blk < 17152) { rel = blk - 12544; s = wq_b; d = wqbb; sc = scaleq; }
  else if (blk < 18176) { rel = blk - 17152; s = wk_b; d = wkvB; }
  else if (blk < 19200) { rel = blk - 18176; s = wv_b; d = wkvB + 1048576; }
  else                  { rel = blk - 19200; s = wo;   d = wob; }
  int i = (rel * 256 + tid) << 2;
  float4 v = *(const float4*)(s + i);
  cvt_store4(d + i, v.x * sc, v.y * sc, v.z * sc, v.w * sc);
}

// ---------------- GEMM: C[M,N] = A[M,K] @ Bw[N,K]^T (all bf16 in) ----------
template <typename TC, int EPI>
__global__ __launch_bounds__(256) void gemm_bt_bf16(
    const bf16* __restrict__ A, const bf16* __restrict__ Bw,
    TC* __restrict__ C0, bf16* __restrict__ C1, int M, int N, int K) {
  __shared__ __align__(16) bf16 As[128 * 64];
  __shared__ __align__(16) bf16 Bs[128 * 64];
  const int tid  = threadIdx.x;
  const int wave = tid >> 6, lane = tid & 63;
  const int m0 = blockIdx.x << 7, n0 = blockIdx.y << 7;
  const int quad = lane >> 4, l16 = lane & 15;
  const int wm = (wave >> 1) << 6, wn = (wave & 1) << 6;
  const int srow = wave << 5;
  const int lrow = lane >> 3;
  const int lcol = (lane & 7) << 3;

  const bf16* gA = A  + (size_t)(m0 + srow + lrow) * K + lcol;
  const bf16* gB = Bw + (size_t)(n0 + srow + lrow) * K + lcol;
  bf16* lA = As + srow * 64;
  bf16* lB = Bs + srow * 64;

  floatx4 acc[4][4];
#pragma unroll
  for (int i = 0; i < 4; i++)
#pragma unroll
    for (int j = 0; j < 4; j++) acc[i][j] = floatx4{0.f, 0.f, 0.f, 0.f};

  for (int k0 = 0; k0 < K; k0 += 64) {
    __syncthreads();
#pragma unroll
    for (int t = 0; t < 4; t++) {
      gl_lds16(gA + (size_t)(t << 3) * K + k0, lA + (t << 3) * 64);
      gl_lds16(gB + (size_t)(t << 3) * K + k0, lB + (t << 3) * 64);
    }
    __syncthreads();
#pragma unroll
    for (int ks = 0; ks < 2; ks++) {
      bf16x8 af[4], bv[4];
#pragma unroll
      for (int i = 0; i < 4; i++)
        af[i] = *(const bf16x8*)&As[(wm + (i << 4) + l16) * 64 + (ks << 5) + (quad << 3)];
#pragma unroll
      for (int j = 0; j < 4; j++)
        bv[j] = *(const bf16x8*)&Bs[(wn + (j << 4) + l16) * 64 + (ks << 5) + (quad << 3)];
#pragma unroll
      for (int i = 0; i < 4; i++)
#pragma unroll
        for (int j = 0; j < 4; j++)
          acc[i][j] = __builtin_amdgcn_mfma_f32_16x16x32_bf16(af[i], bv[j], acc[i][j], 0, 0, 0);
    }
  }

  if constexpr (EPI == 1) {
    if (n0 >= 2048) {
#pragma unroll
      for (int i = 0; i < 4; i++) {
        int gm = m0 + wm + (i << 4) + (quad << 2);
        int bb = gm >> 10, s = gm & 1023;
#pragma unroll
        for (int j = 0; j < 4; j++) {
          int gn = n0 + wn + (j << 4) + l16 - 2048;
          int hh = gn >> 7, vd = gn & 127;
          union { bf16 h4[4]; uint2 u; } pk;
#pragma unroll
          for (int r = 0; r < 4; r++) pk.h4[r] = (bf16)acc[i][j][r];
          *(uint2*)(C1 + ((((size_t)bb * HH + hh) * DV + vd) << 10) + s) = pk.u;
        }
      }
      return;
    }
  }
  const int ldc = (EPI == 1) ? 2048 : N;
#pragma unroll
  for (int i = 0; i < 4; i++)
#pragma unroll
    for (int j = 0; j < 4; j++) {
      int gn = n0 + wn + (j << 4) + l16;
#pragma unroll
      for (int r = 0; r < 4; r++) {
        int gm = m0 + wm + (i << 4) + (quad << 2) + r;
        C0[(size_t)gm * ldc + gn] = (TC)acc[i][j][r];
      }
    }
}

// ---------------- fused rmsnorm(q) + rmsnorm(kv) + rope_k ----------------
__global__ __launch_bounds__(256) void norm_rope(
    const bf16* __restrict__ xout, const float* __restrict__ w_qa_ln,
    const float* __restrict__ w_kva_ln, bf16* __restrict__ qln,
    bf16* __restrict__ ckv, bf16* __restrict__ kpe,
    const float* __restrict__ rsin, const float* __restrict__ rcos) {
  const int blk = blockIdx.x, tid = threadIdx.x;
  if (blk < 8192) {
    const int row = blk & 4095;
    const bool isq = blk < 4096;
    const bf16* p = xout + (size_t)row * XOUTW + (isq ? 0 : QLR);
    const float* w = isq ? w_qa_ln : w_kva_ln;
    bf16* o = isq ? (qln + (size_t)row * QLR) : (ckv + (size_t)row * KVLR);
    const int L = isq ? QLR : KVLR;
    float ss = 0.f;
    for (int c = tid << 2; c < L; c += 1024) {
      union { uint2 u; bf16 h[4]; } t;
      t.u = *(const uint2*)(p + c);
#pragma unroll
      for (int r = 0; r < 4; r++) { float v = (float)t.h[r]; ss += v * v; }
    }
#pragma unroll
    for (int off = 32; off > 0; off >>= 1) ss += __shfl_down(ss, off);
    __shared__ float red[4];
    if ((tid & 63) == 0) red[tid >> 6] = ss;
    __syncthreads();
    float rs = rsqrtf((red[0] + red[1] + red[2] + red[3]) / (float)L + EPSF);
    for (int c = tid << 2; c < L; c += 1024) {
      union { uint2 u; bf16 h[4]; } t, ot;
      t.u = *(const uint2*)(p + c);
#pragma unroll
      for (int r = 0; r < 4; r++) ot.h[r] = (bf16)((float)t.h[r] * rs * w[c + r]);
      *(uint2*)(o + c) = ot.u;
    }
  } else {
    int idx = (blk - 8192) * 256 + tid;   // NTOK*32
    int i = idx & 31, row = idx >> 5;
    int pos = row & (SS - 1);
    union { uint u; bf16 h2[2]; } t;
    t.u = *(const uint*)(xout + (size_t)row * XOUTW + QLR + KVLR + (i << 1));
    float e = (float)t.h2[0], o = (float)t.h2[1];
    float c = rcos[(pos << 5) + i], s = rsin[(pos << 5) + i];
    t.h2[0] = (bf16)(e * c - o * s);
    t.h2[1] = (bf16)(e * s + o * c);
    *(uint*)(kpe + (size_t)row * DROPE + (i << 1)) = t.u;
  }
}

// ---------------- rope q (interleaved, bf16, in place) ----------------
__global__ void rope_q(bf16* __restrict__ q, const float* __restrict__ sin_t,
                       const float* __restrict__ cos_t) {
  int idx = blockIdx.x * 256 + threadIdx.x;   // NTOK*HH*32
  int i = idx & 31, h = (idx >> 5) & 15, row = idx >> 9;
  int pos = row & (SS - 1);
  bf16* base = q + ((size_t)row * HH + h) * DQK + DNOPE + (i << 1);
  union { uint u; bf16 h2[2]; } t;
  t.u = *(uint*)base;
  float e = (float)t.h2[0], o = (float)t.h2[1];
  float c = cos_t[(pos << 5) + i], s = sin_t[(pos << 5) + i];
  t.h2[0] = (bf16)(e * c - o * s);
  t.h2[1] = (bf16)(e * s + o * c);
  *(uint*)base = t.u;
}

// ---------------- flash attention ----------------
// grid (8, H, B) reversed-qt; 512 thr = 8 waves; wave w owns q rows
// [w*16, w*16+16) of a 128-row tile. K/V staged per 64-key slot via
// global_load_lds (async DMA, no VGPR prefetch state -> no spill) into
// XOR-swizzled unpadded LDS tiles (sbi = bi ^ (row&mask) on 16B blocks:
// staging computes the inverse map on per-lane GLOBAL addresses; fragment
// reads land 2-way per bank = free). m97-style 2-barrier slot loop; latency
// covered by DMA-in-flight + 2 blocks/CU.
__global__ __launch_bounds__(512) void attn_kernel(
    const bf16* __restrict__ q, const bf16* __restrict__ knope,
    const bf16* __restrict__ kpe, const bf16* __restrict__ vT,
    bf16* __restrict__ out) {
  const int qt = 7 - blockIdx.x;
  const int q0 = qt << 7;
  const int nkt = (qt << 1) + 2;
  const int h = blockIdx.y, b = blockIdx.z;
  __shared__ __align__(16) bf16 smem[20480];     // 40 KB: Kn|Kp|Vt (+Q staging overlay)
  __shared__ __align__(16) bf16 Ps[8][16][72];   // 18.4 KB per-wave P
  __shared__ float alphaS[8][16], invlS[8][16];
  bf16* Kn = smem;          // [64][128] swizzled (8192 elems)
  bf16* Kp = smem + 8192;   // [64][64]  swizzled (4096 elems)
  bf16* Vt = smem + 12288;  // [128][64] swizzled (8192 elems)
  const int tid = threadIdx.x, wave = tid >> 6, lane = tid & 63;
  const int quad = lane >> 4, l16 = lane & 15;

  // ---- Q fragments: two staging rounds via smem viewed as [64][200] ----
  bf16x8 aq[6];
  for (int round = 0; round < 2; round++) {
    __syncthreads();
    for (int i = tid; i < 64 * 24; i += 512) {
      int r = i / 24, c = (i % 24) << 3;
      *(uint4*)&smem[r * 200 + c] = *(const uint4*)(
          q + ((size_t)((b << 10) + q0 + (round << 6) + r) * HH + h) * DQK + c);
    }
    __syncthreads();
    if ((wave >> 2) == round) {
      int rw = wave & 3;
#pragma unroll
      for (int t = 0; t < 6; t++)
        aq[t] = *(const bf16x8*)&smem[((rw << 4) + l16) * 200 + (t << 5) + (quad << 3)];
    }
  }

  // ---- per-lane global staging addresses (slot 0), swizzle inverse map ----
  const bf16 *gkn0, *gkn1, *gkp, *gvt0, *gvt1;
  {
    int c = wave << 1;                       // Kn chunk u=0 (4 rows / 1KB)
    int r = (c << 2) + (lane >> 4);
    int bi = (lane & 15) ^ (r & 15);
    gkn0 = knope + ((size_t)((b << 10) + r) * HH + h) * DNOPE + (bi << 3);
    r = ((c + 1) << 2) + (lane >> 4);        // u=1
    bi = (lane & 15) ^ (r & 15);
    gkn1 = knope + ((size_t)((b << 10) + r) * HH + h) * DNOPE + (bi << 3);
    r = (wave << 3) + (lane >> 3);           // Kp chunk (8 rows / 1KB)
    bi = (lane & 7) ^ (r & 7);
    gkp = kpe + (size_t)((b << 10) + r) * DROPE + (bi << 3);
    int dv = (wave << 4) + (lane >> 3);      // Vt chunk u=0
    bi = (lane & 7) ^ (dv & 7);
    gvt0 = vT + ((((size_t)b * HH + h) * DV + dv) << 10) + (bi << 3);
    dv += 8;                                 // u=1
    bi = (lane & 7) ^ (dv & 7);
    gvt1 = vT + ((((size_t)b * HH + h) * DV + dv) << 10) + (bi << 3);
  }
  bf16* lkn0 = Kn + (wave << 10);
  bf16* lkn1 = Kn + (wave << 10) + 512;
  bf16* lkp  = Kp + (wave << 9);
  bf16* lvt0 = Vt + (wave << 10);
  bf16* lvt1 = Vt + (wave << 10) + 512;
  const size_t knstep = (size_t)64 * HH * DNOPE;
  const size_t kpstep = (size_t)64 * DROPE;

  floatx4 acc_o[8];
#pragma unroll
  for (int n = 0; n < 8; n++) acc_o[n] = floatx4{0.f, 0.f, 0.f, 0.f};
  float m_i[4], l_i[4];
#pragma unroll
  for (int r = 0; r < 4; r++) { m_i[r] = -1e30f; l_i[r] = 0.f; }

  for (int s = 0; s < nkt; s++) {
    __syncthreads();                 // prev slot's LDS reads (and Q rounds) done
    gl_lds16(gkn0, lkn0);
    gl_lds16(gkn1, lkn1);
    gl_lds16(gkp,  lkp);
    gl_lds16(gvt0, lvt0);
    gl_lds16(gvt1, lvt1);
    gkn0 += knstep; gkn1 += knstep; gkp += kpstep; gvt0 += 64; gvt1 += 64;
    __syncthreads();                 // drains vmcnt (DMA landed)

    // QK^T: 16(q) x 64(k) per wave; swizzled b-frag reads
    floatx4 sacc[4];
#pragma unroll
    for (int kn = 0; kn < 4; kn++) {
      floatx4 sc = floatx4{0.f, 0.f, 0.f, 0.f};
#pragma unroll
      for (int t = 0; t < 4; t++) {
        int sbi = ((t << 2) + quad) ^ l16;
        bf16x8 bk = *(const bf16x8*)&Kn[(((kn << 4) + l16) << 7) + (sbi << 3)];
        sc = __builtin_amdgcn_mfma_f32_16x16x32_bf16(aq[t], bk, sc, 0, 0, 0);
      }
#pragma unroll
      for (int t = 0; t < 2; t++) {
        int sbi = ((t << 2) + quad) ^ (l16 & 7);
        bf16x8 bk = *(const bf16x8*)&Kp[(((kn << 4) + l16) << 6) + (sbi << 3)];
        sc = __builtin_amdgcn_mfma_f32_16x16x32_bf16(aq[4 + t], bk, sc, 0, 0, 0);
      }
      sacc[kn] = sc;
    }

    // mask (diagonal slots only) + online softmax (exp2 domain)
    const int k0 = s << 6;
    float pvv[4][4], mtile[4];
#pragma unroll
    for (int r = 0; r < 4; r++) mtile[r] = -1e30f;
    if (s >= nkt - 2) {
#pragma unroll
      for (int kn = 0; kn < 4; kn++)
#pragma unroll
        for (int r = 0; r < 4; r++) {
          int qg = q0 + (wave << 4) + (quad << 2) + r;
          int kg = k0 + (kn << 4) + l16;
          float sv = sacc[kn][r];
          if (kg > qg) sv = -1e30f;
          pvv[kn][r] = sv;
          mtile[r] = fmaxf(mtile[r], sv);
        }
    } else {
#pragma unroll
      for (int kn = 0; kn < 4; kn++)
#pragma unroll
        for (int r = 0; r < 4; r++) {
          float sv = sacc[kn][r];
          pvv[kn][r] = sv;
          mtile[r] = fmaxf(mtile[r], sv);
        }
    }
    float alpha[4];
#pragma unroll
    for (int r = 0; r < 4; r++) {
#pragma unroll
      for (int off = 1; off < 16; off <<= 1)
        mtile[r] = fmaxf(mtile[r], __shfl_xor(mtile[r], off));
      float mnew = fmaxf(m_i[r], mtile[r]);
      alpha[r] = exp2f(m_i[r] - mnew);
      m_i[r] = mnew;
      float part = 0.f;
#pragma unroll
      for (int kn = 0; kn < 4; kn++) {
        float p = exp2f(pvv[kn][r] - mnew);
        pvv[kn][r] = p;
        part += p;
      }
#pragma unroll
      for (int off = 1; off < 16; off <<= 1) part += __shfl_xor(part, off);
      l_i[r] = l_i[r] * alpha[r] + part;
    }
    // P -> LDS (wave-private slice)
#pragma unroll
    for (int kn = 0; kn < 4; kn++)
#pragma unroll
      for (int r = 0; r < 4; r++)
        Ps[wave][(quad << 2) + r][(kn << 4) + l16] = (bf16)pvv[kn][r];
    if (l16 == 0)
      *(float4*)&alphaS[wave][quad << 2] =
          make_float4(alpha[0], alpha[1], alpha[2], alpha[3]);
    float alpha_lane = alphaS[wave][l16];
#pragma unroll
    for (int n = 0; n < 8; n++)
#pragma unroll
      for (int r = 0; r < 4; r++) acc_o[n][r] *= alpha_lane;

    // O^T += V^T * P^T  (A = swizzled Vt frags, B = P frags)
    bf16x8 bp[2];
#pragma unroll
    for (int t = 0; t < 2; t++)
      bp[t] = *(const bf16x8*)&Ps[wave][l16][(t << 5) + (quad << 3)];
#pragma unroll
    for (int n = 0; n < 8; n++) {
#pragma unroll
      for (int t = 0; t < 2; t++) {
        int sbi = ((t << 2) + quad) ^ (l16 & 7);
        bf16x8 av = *(const bf16x8*)&Vt[(((n << 4) + l16) << 6) + (sbi << 3)];
        acc_o[n] = __builtin_amdgcn_mfma_f32_16x16x32_bf16(av, bp[t], acc_o[n], 0, 0, 0);
      }
    }
  }

  // epilogue: O^T C-layout -> lane holds q=l16, dv = n*16+quad*4+r (8B stores)
  if (l16 == 0)
    *(float4*)&invlS[wave][quad << 2] =
        make_float4(1.f / l_i[0], 1.f / l_i[1], 1.f / l_i[2], 1.f / l_i[3]);
  float invl = invlS[wave][l16];
  int tok = (b << 10) + q0 + (wave << 4) + l16;
  bf16* obase = out + ((size_t)tok * HH + h) * DV + (quad << 2);
#pragma unroll
  for (int n = 0; n < 8; n++) {
    union { bf16 h4[4]; uint2 u; } pk;
#pragma unroll
    for (int r = 0; r < 4; r++) pk.h4[r] = (bf16)(acc_o[n][r] * invl);
    *(uint2*)(obase + (n << 4)) = pk.u;
  }
}

// ---------------- launch ----------------
extern "C" void kernel_launch(void* const* d_in, const int* in_sizes, int n_in,
                              void* d_out, int out_size, void* d_ws, size_t ws_size,
                              hipStream_t stream) {
  (void)in_sizes; (void)n_in; (void)out_size; (void)ws_size;
  const float* x        = (const float*)d_in[0];
  const float* wq_a     = (const float*)d_in[1];
  const float* w_qa_ln  = (const float*)d_in[2];
  const float* wq_b     = (const float*)d_in[3];
  const float* wkv_a    = (const float*)d_in[4];
  const float* w_kva_ln = (const float*)d_in[5];
  const float* wk_b     = (const float*)d_in[6];
  const float* wv_b     = (const float*)d_in[7];
  const float* wo       = (const float*)d_in[8];
  const float* rsin     = (const float*)d_in[9];
  const float* rcos     = (const float*)d_in[10];
  float* out = (float*)d_out;

  // workspace (liveness-aliased), total ~112.2 MB
  char* ws = (char*)d_ws;
  bf16* xb    = (bf16*)(ws + 0);            // 16.78M, dead after xout gemm
  bf16* attnb = (bf16*)(ws + 0);            //   aliases xb
  bf16* xout  = (bf16*)(ws + 16777216);     // 17.83M [4096][2176]
  bf16* knope = (bf16*)(ws + 16777216);     //   aliases xout, stride 2048
  bf16* q     = (bf16*)(ws + 34603008);     // 25.17M
  bf16* qln   = (bf16*)(ws + 59768832);     // 12.58M, dead after q gemm
  bf16* vT    = (bf16*)(ws + 59768832);     //   aliases qln
  bf16* wA    = (bf16*)(ws + 76546048);     // 8.91M  [2176][2048]
  bf16* wqbb  = (bf16*)(ws + 85458944);     // 9.44M
  bf16* wkvB  = (bf16*)(ws + 94896128);     // 4.19M  [4096][512]
  bf16* wob   = (bf16*)(ws + 99090432);     // 8.39M
  bf16* ckv   = (bf16*)(ws + 107479040);    // 4.19M
  bf16* kpe   = (bf16*)(ws + 111673344);    // 0.52M -> end 112197632

  const float SCALEQ = (1.0f / sqrtf(192.0f)) * 1.44269504088896f;

  dim3 blk(256);
  cvt_all<<<23296, blk, 0, stream>>>(x, wq_a, wkv_a, wq_b, wk_b, wv_b, wo,
                                     xb, wA, wqbb, wkvB, wob, SCALEQ);
  // xout = xb @ [wq_a ; wkv_a]^T
  gemm_bt_bf16<bf16, 0><<<dim3(32, 17), blk, 0, stream>>>(
      xb, wA, xout, nullptr, NTOK, XOUTW, HID);
  // rmsnorm(q), rmsnorm(kv), rope_k in one dispatch
  norm_rope<<<8704, blk, 0, stream>>>(xout, w_qa_ln, w_kva_ln, qln, ckv, kpe,
                                      rsin, rcos);
  // q = qln @ wq_b^T (pre-scaled by SCALEQ)
  gemm_bt_bf16<bf16, 0><<<dim3(32, 24), blk, 0, stream>>>(
      qln, wqbb, q, nullptr, NTOK, HH * DQK, QLR);
  rope_q<<<8192, blk, 0, stream>>>(q, rsin, rcos);
  // [knope | vT] = ckv @ [wk_b ; wv_b]^T (dual epilogue)
  gemm_bt_bf16<bf16, 1><<<dim3(32, 32), blk, 0, stream>>>(
      ckv, wkvB, knope, vT, NTOK, 4096, KVLR);
  attn_kernel<<<dim3(8, HH, BB), dim3(512), 0, stream>>>(
      q, knope, kpe, vT, attnb);
  gemm_bt_bf16<float, 0><<<dim3(32, 16), blk, 0, stream>>>(
      attnb, wob, out, nullptr, NTOK, HID, HID);
}

// Round 7
// 489.858 us; speedup vs baseline: 1.1856x; 1.0245x over previous
//
#include <hip/hip_runtime.h>
#include <stdint.h>

typedef __bf16 bf16;
typedef __bf16 bf16x8 __attribute__((ext_vector_type(8)));
typedef float floatx4 __attribute__((ext_vector_type(4)));

#define HH     16
#define DNOPE  128
#define DROPE  64
#define DV     128
#define DQK    192
#define HID    2048
#define QLR    1536
#define KVLR   512
#define BB     4
#define SS     1024
#define NTOK   4096
#define XOUTW  2176
#define EPSF   1e-6f

// ---------------- helpers ----------------
__device__ inline void cvt_store4(bf16* dst, float a, float b, float c, float d) {
  union { bf16 h[4]; uint2 u; } t;
  t.h[0] = (bf16)a; t.h[1] = (bf16)b; t.h[2] = (bf16)c; t.h[3] = (bf16)d;
  *(uint2*)dst = t.u;
}

__device__ inline void gl_lds16(const bf16* g, bf16* l) {
  __builtin_amdgcn_global_load_lds(
      (const __attribute__((address_space(1))) void*)g,
      (__attribute__((address_space(3))) void*)l, 16, 0, 0);
}

// ---------------- merged fp32 -> bf16 conversion (all weights + x) --------
__global__ __launch_bounds__(256) void cvt_all(
    const float* __restrict__ x, const float* __restrict__ wq_a,
    const float* __restrict__ wkv_a, const float* __restrict__ wq_b,
    const float* __restrict__ wk_b, const float* __restrict__ wv_b,
    const float* __restrict__ wo, bf16* __restrict__ xb,
    bf16* __restrict__ wA, bf16* __restrict__ wqbb,
    bf16* __restrict__ wkvB, bf16* __restrict__ wob, float scaleq) {
  const int blk = blockIdx.x, tid = threadIdx.x;
  const float* s; bf16* d; int rel; float sc = 1.0f;
  if (blk < 8192)       { rel = blk;         s = x;    d = xb; }
  else if (blk < 11264) { rel = blk - 8192;  s = wq_a; d = wA; }
  else if (blk < 12544) { // wkv_a pad to 640 rows
    rel = blk - 11264;
    int i = (rel * 256 + tid) << 2;
    bf16* dd = wA + 3145728;
    if ((i >> 11) < 576) {
      float4 v = *(const float4*)(wkv_a + i);
      cvt_store4(dd + i, v.x, v.y, v.z, v.w);
    } else {
      *(uint2*)(dd + i) = make_uint2(0u, 0u);
    }
    return;
  }
  else if (blk < 17152) { rel = blk - 12544; s = wq_b; d = wqbb; sc = scaleq; }
  else if (blk < 18176) { rel = blk - 17152; s = wk_b; d = wkvB; }
  else if (blk < 19200) { rel = blk - 18176; s = wv_b; d = wkvB + 1048576; }
  else                  { rel = blk - 19200; s = wo;   d = wob; }
  int i = (rel * 256 + tid) << 2;
  float4 v = *(const float4*)(s + i);
  cvt_store4(d + i, v.x * sc, v.y * sc, v.z * sc, v.w * sc);
}

// ---------------- GEMM: C[M,N] = A[M,K] @ Bw[N,K]^T (all bf16 in) ----------
template <typename TC, int EPI>
__global__ __launch_bounds__(256) void gemm_bt_bf16(
    const bf16* __restrict__ A, const bf16* __restrict__ Bw,
    TC* __restrict__ C0, bf16* __restrict__ C1, int M, int N, int K) {
  __shared__ __align__(16) bf16 As[128 * 64];
  __shared__ __align__(16) bf16 Bs[128 * 64];
  const int tid  = threadIdx.x;
  const int wave = tid >> 6, lane = tid & 63;
  const int m0 = blockIdx.x << 7, n0 = blockIdx.y << 7;
  const int quad = lane >> 4, l16 = lane & 15;
  const int wm = (wave >> 1) << 6, wn = (wave & 1) << 6;
  const int srow = wave << 5;
  const int lrow = lane >> 3;
  const int lcol = (lane & 7) << 3;

  const bf16* gA = A  + (size_t)(m0 + srow + lrow) * K + lcol;
  const bf16* gB = Bw + (size_t)(n0 + srow + lrow) * K + lcol;
  bf16* lA = As + srow * 64;
  bf16* lB = Bs + srow * 64;

  floatx4 acc[4][4];
#pragma unroll
  for (int i = 0; i < 4; i++)
#pragma unroll
    for (int j = 0; j < 4; j++) acc[i][j] = floatx4{0.f, 0.f, 0.f, 0.f};

  for (int k0 = 0; k0 < K; k0 += 64) {
    __syncthreads();
#pragma unroll
    for (int t = 0; t < 4; t++) {
      gl_lds16(gA + (size_t)(t << 3) * K + k0, lA + (t << 3) * 64);
      gl_lds16(gB + (size_t)(t << 3) * K + k0, lB + (t << 3) * 64);
    }
    __syncthreads();
#pragma unroll
    for (int ks = 0; ks < 2; ks++) {
      bf16x8 af[4], bv[4];
#pragma unroll
      for (int i = 0; i < 4; i++)
        af[i] = *(const bf16x8*)&As[(wm + (i << 4) + l16) * 64 + (ks << 5) + (quad << 3)];
#pragma unroll
      for (int j = 0; j < 4; j++)
        bv[j] = *(const bf16x8*)&Bs[(wn + (j << 4) + l16) * 64 + (ks << 5) + (quad << 3)];
#pragma unroll
      for (int i = 0; i < 4; i++)
#pragma unroll
        for (int j = 0; j < 4; j++)
          acc[i][j] = __builtin_amdgcn_mfma_f32_16x16x32_bf16(af[i], bv[j], acc[i][j], 0, 0, 0);
    }
  }

  if constexpr (EPI == 1) {
    if (n0 >= 2048) {
#pragma unroll
      for (int i = 0; i < 4; i++) {
        int gm = m0 + wm + (i << 4) + (quad << 2);
        int bb = gm >> 10, s = gm & 1023;
#pragma unroll
        for (int j = 0; j < 4; j++) {
          int gn = n0 + wn + (j << 4) + l16 - 2048;
          int hh = gn >> 7, vd = gn & 127;
          union { bf16 h4[4]; uint2 u; } pk;
#pragma unroll
          for (int r = 0; r < 4; r++) pk.h4[r] = (bf16)acc[i][j][r];
          *(uint2*)(C1 + ((((size_t)bb * HH + hh) * DV + vd) << 10) + s) = pk.u;
        }
      }
      return;
    }
  }
  const int ldc = (EPI == 1) ? 2048 : N;
#pragma unroll
  for (int i = 0; i < 4; i++)
#pragma unroll
    for (int j = 0; j < 4; j++) {
      int gn = n0 + wn + (j << 4) + l16;
#pragma unroll
      for (int r = 0; r < 4; r++) {
        int gm = m0 + wm + (i << 4) + (quad << 2) + r;
        C0[(size_t)gm * ldc + gn] = (TC)acc[i][j][r];
      }
    }
}

// ---------------- fused rmsnorm(q) + rmsnorm(kv) + rope_k ----------------
__global__ __launch_bounds__(256) void norm_rope(
    const bf16* __restrict__ xout, const float* __restrict__ w_qa_ln,
    const float* __restrict__ w_kva_ln, bf16* __restrict__ qln,
    bf16* __restrict__ ckv, bf16* __restrict__ kpe,
    const float* __restrict__ rsin, const float* __restrict__ rcos) {
  const int blk = blockIdx.x, tid = threadIdx.x;
  if (blk < 8192) {
    const int row = blk & 4095;
    const bool isq = blk < 4096;
    const bf16* p = xout + (size_t)row * XOUTW + (isq ? 0 : QLR);
    const float* w = isq ? w_qa_ln : w_kva_ln;
    bf16* o = isq ? (qln + (size_t)row * QLR) : (ckv + (size_t)row * KVLR);
    const int L = isq ? QLR : KVLR;
    float ss = 0.f;
    for (int c = tid << 2; c < L; c += 1024) {
      union { uint2 u; bf16 h[4]; } t;
      t.u = *(const uint2*)(p + c);
#pragma unroll
      for (int r = 0; r < 4; r++) { float v = (float)t.h[r]; ss += v * v; }
    }
#pragma unroll
    for (int off = 32; off > 0; off >>= 1) ss += __shfl_down(ss, off);
    __shared__ float red[4];
    if ((tid & 63) == 0) red[tid >> 6] = ss;
    __syncthreads();
    float rs = rsqrtf((red[0] + red[1] + red[2] + red[3]) / (float)L + EPSF);
    for (int c = tid << 2; c < L; c += 1024) {
      union { uint2 u; bf16 h[4]; } t, ot;
      t.u = *(const uint2*)(p + c);
#pragma unroll
      for (int r = 0; r < 4; r++) ot.h[r] = (bf16)((float)t.h[r] * rs * w[c + r]);
      *(uint2*)(o + c) = ot.u;
    }
  } else {
    int idx = (blk - 8192) * 256 + tid;   // NTOK*32
    int i = idx & 31, row = idx >> 5;
    int pos = row & (SS - 1);
    union { uint u; bf16 h2[2]; } t;
    t.u = *(const uint*)(xout + (size_t)row * XOUTW + QLR + KVLR + (i << 1));
    float e = (float)t.h2[0], o = (float)t.h2[1];
    float c = rcos[(pos << 5) + i], s = rsin[(pos << 5) + i];
    t.h2[0] = (bf16)(e * c - o * s);
    t.h2[1] = (bf16)(e * s + o * c);
    *(uint*)(kpe + (size_t)row * DROPE + (i << 1)) = t.u;
  }
}

// ---------------- rope q (interleaved, bf16, in place) ----------------
__global__ void rope_q(bf16* __restrict__ q, const float* __restrict__ sin_t,
                       const float* __restrict__ cos_t) {
  int idx = blockIdx.x * 256 + threadIdx.x;   // NTOK*HH*32
  int i = idx & 31, h = (idx >> 5) & 15, row = idx >> 9;
  int pos = row & (SS - 1);
  bf16* base = q + ((size_t)row * HH + h) * DQK + DNOPE + (i << 1);
  union { uint u; bf16 h2[2]; } t;
  t.u = *(uint*)base;
  float e = (float)t.h2[0], o = (float)t.h2[1];
  float c = cos_t[(pos << 5) + i], s = sin_t[(pos << 5) + i];
  t.h2[0] = (bf16)(e * c - o * s);
  t.h2[1] = (bf16)(e * s + o * c);
  *(uint*)base = t.u;
}

// ---------------- flash attention (1-barrier pipelined K-loop) ------------
// grid (8, H, B) reversed-qt; 512 thr = 8 waves. Double-buffered 40KB K/V
// LDS staged via global_load_lds. Per slot: {s_waitcnt vmcnt(0); s_barrier}
// (raw asm: NO full-drain after next-slot issue), then issue slot s+1's DMA
// into the other buffer, then compute slot s — DMA flies across the whole
// compute phase (AITER-style). XOR-swizzled tiles as in R6. 1 block/CU.
__global__ __launch_bounds__(512) void attn_kernel(
    const bf16* __restrict__ q, const bf16* __restrict__ knope,
    const bf16* __restrict__ kpe, const bf16* __restrict__ vT,
    bf16* __restrict__ out) {
  const int qt = 7 - blockIdx.x;
  const int q0 = qt << 7;
  const int nkt = (qt << 1) + 2;
  const int h = blockIdx.y, b = blockIdx.z;
  __shared__ __align__(16) bf16 smem[40960];     // 2 x 40KB K/V buffers
  __shared__ __align__(16) bf16 Ps[8][16][72];
  __shared__ float alphaS[8][16], invlS[8][16];
  // buffer layout (within 20480-elem buf): Kn [0,8192) Kp [8192,12288) Vt [12288,20480)
  const int tid = threadIdx.x, wave = tid >> 6, lane = tid & 63;
  const int quad = lane >> 4, l16 = lane & 15;

  // ---- per-lane global staging addresses (slot 0), swizzle inverse map ----
  const bf16 *gkn0, *gkn1, *gkp, *gvt0, *gvt1;
  {
    int c = wave << 1;
    int r = (c << 2) + (lane >> 4);
    int bi = (lane & 15) ^ (r & 15);
    gkn0 = knope + ((size_t)((b << 10) + r) * HH + h) * DNOPE + (bi << 3);
    r = ((c + 1) << 2) + (lane >> 4);
    bi = (lane & 15) ^ (r & 15);
    gkn1 = knope + ((size_t)((b << 10) + r) * HH + h) * DNOPE + (bi << 3);
    r = (wave << 3) + (lane >> 3);
    bi = (lane & 7) ^ (r & 7);
    gkp = kpe + (size_t)((b << 10) + r) * DROPE + (bi << 3);
    int dv = (wave << 4) + (lane >> 3);
    bi = (lane & 7) ^ (dv & 7);
    gvt0 = vT + ((((size_t)b * HH + h) * DV + dv) << 10) + (bi << 3);
    dv += 8;
    bi = (lane & 7) ^ (dv & 7);
    gvt1 = vT + ((((size_t)b * HH + h) * DV + dv) << 10) + (bi << 3);
  }
  const size_t knstep = (size_t)64 * HH * DNOPE;
  const size_t kpstep = (size_t)64 * DROPE;
  const int woff = wave << 10, woff2 = wave << 9;

  // issue slot-0 DMA into buf0 (overlaps Q staging which uses buf1 region)
  {
    bf16* bufp = smem;
    gl_lds16(gkn0, bufp + woff);
    gl_lds16(gkn1, bufp + woff + 512);
    gl_lds16(gkp,  bufp + 8192 + woff2);
    gl_lds16(gvt0, bufp + 12288 + woff);
    gl_lds16(gvt1, bufp + 12288 + woff + 512);
    gkn0 += knstep; gkn1 += knstep; gkp += kpstep; gvt0 += 64; gvt1 += 64;
  }

  // ---- Q fragments: two staging rounds via buf1 region viewed [64][200] ----
  bf16x8 aq[6];
  bf16* qov = smem + 20480;
  for (int round = 0; round < 2; round++) {
    __syncthreads();
    for (int i = tid; i < 64 * 24; i += 512) {
      int r = i / 24, c = (i % 24) << 3;
      *(uint4*)&qov[r * 200 + c] = *(const uint4*)(
          q + ((size_t)((b << 10) + q0 + (round << 6) + r) * HH + h) * DQK + c);
    }
    __syncthreads();
    if ((wave >> 2) == round) {
      int rw = wave & 3;
#pragma unroll
      for (int t = 0; t < 6; t++)
        aq[t] = *(const bf16x8*)&qov[((rw << 4) + l16) * 200 + (t << 5) + (quad << 3)];
    }
  }
  // ensure overlay ds_reads retired before slot-1 DMA overwrites buf1
  asm volatile("s_waitcnt lgkmcnt(0)" ::: "memory");

  floatx4 acc_o[8];
#pragma unroll
  for (int n = 0; n < 8; n++) acc_o[n] = floatx4{0.f, 0.f, 0.f, 0.f};
  float m_i[4], l_i[4];
#pragma unroll
  for (int r = 0; r < 4; r++) { m_i[r] = -1e30f; l_i[r] = 0.f; }

  for (int s = 0; s < nkt; s++) {
    // slot-s DMA (only outstanding vmem) drained per-wave, then barrier:
    // all waves have slot-s data; all waves done computing slot s-1.
    asm volatile("s_waitcnt vmcnt(0)\n\ts_barrier" ::: "memory");
    if (s + 1 < nkt) {   // issue slot s+1 into the other buffer
      bf16* bufp = smem + ((s + 1) & 1) * 20480;
      gl_lds16(gkn0, bufp + woff);
      gl_lds16(gkn1, bufp + woff + 512);
      gl_lds16(gkp,  bufp + 8192 + woff2);
      gl_lds16(gvt0, bufp + 12288 + woff);
      gl_lds16(gvt1, bufp + 12288 + woff + 512);
      gkn0 += knstep; gkn1 += knstep; gkp += kpstep; gvt0 += 64; gvt1 += 64;
    }
    __builtin_amdgcn_sched_barrier(0);   // pin DMA issue before compute

    const bf16* Kn = smem + (s & 1) * 20480;
    const bf16* Kp = Kn + 8192;
    const bf16* Vt = Kn + 12288;

    // QK^T: 16(q) x 64(k) per wave; swizzled b-frag reads
    floatx4 sacc[4];
#pragma unroll
    for (int kn = 0; kn < 4; kn++) {
      floatx4 sc = floatx4{0.f, 0.f, 0.f, 0.f};
#pragma unroll
      for (int t = 0; t < 4; t++) {
        int sbi = ((t << 2) + quad) ^ l16;
        bf16x8 bk = *(const bf16x8*)&Kn[(((kn << 4) + l16) << 7) + (sbi << 3)];
        sc = __builtin_amdgcn_mfma_f32_16x16x32_bf16(aq[t], bk, sc, 0, 0, 0);
      }
#pragma unroll
      for (int t = 0; t < 2; t++) {
        int sbi = ((t << 2) + quad) ^ (l16 & 7);
        bf16x8 bk = *(const bf16x8*)&Kp[(((kn << 4) + l16) << 6) + (sbi << 3)];
        sc = __builtin_amdgcn_mfma_f32_16x16x32_bf16(aq[4 + t], bk, sc, 0, 0, 0);
      }
      sacc[kn] = sc;
    }

    // mask (diagonal slots only) + online softmax (exp2 domain)
    const int k0 = s << 6;
    float pvv[4][4], mtile[4];
#pragma unroll
    for (int r = 0; r < 4; r++) mtile[r] = -1e30f;
    if (s >= nkt - 2) {
#pragma unroll
      for (int kn = 0; kn < 4; kn++)
#pragma unroll
        for (int r = 0; r < 4; r++) {
          int qg = q0 + (wave << 4) + (quad << 2) + r;
          int kg = k0 + (kn << 4) + l16;
          float sv = sacc[kn][r];
          if (kg > qg) sv = -1e30f;
          pvv[kn][r] = sv;
          mtile[r] = fmaxf(mtile[r], sv);
        }
    } else {
#pragma unroll
      for (int kn = 0; kn < 4; kn++)
#pragma unroll
        for (int r = 0; r < 4; r++) {
          float sv = sacc[kn][r];
          pvv[kn][r] = sv;
          mtile[r] = fmaxf(mtile[r], sv);
        }
    }
    float alpha[4];
#pragma unroll
    for (int r = 0; r < 4; r++) {
#pragma unroll
      for (int off = 1; off < 16; off <<= 1)
        mtile[r] = fmaxf(mtile[r], __shfl_xor(mtile[r], off));
      float mnew = fmaxf(m_i[r], mtile[r]);
      alpha[r] = exp2f(m_i[r] - mnew);
      m_i[r] = mnew;
      float part = 0.f;
#pragma unroll
      for (int kn = 0; kn < 4; kn++) {
        float p = exp2f(pvv[kn][r] - mnew);
        pvv[kn][r] = p;
        part += p;
      }
#pragma unroll
      for (int off = 1; off < 16; off <<= 1) part += __shfl_xor(part, off);
      l_i[r] = l_i[r] * alpha[r] + part;
    }
    // P -> LDS (wave-private slice)
#pragma unroll
    for (int kn = 0; kn < 4; kn++)
#pragma unroll
      for (int r = 0; r < 4; r++)
        Ps[wave][(quad << 2) + r][(kn << 4) + l16] = (bf16)pvv[kn][r];
    if (l16 == 0)
      *(float4*)&alphaS[wave][quad << 2] =
          make_float4(alpha[0], alpha[1], alpha[2], alpha[3]);
    float alpha_lane = alphaS[wave][l16];
#pragma unroll
    for (int n = 0; n < 8; n++)
#pragma unroll
      for (int r = 0; r < 4; r++) acc_o[n][r] *= alpha_lane;

    // O^T += V^T * P^T  (A = swizzled Vt frags, B = P frags)
    bf16x8 bp[2];
#pragma unroll
    for (int t = 0; t < 2; t++)
      bp[t] = *(const bf16x8*)&Ps[wave][l16][(t << 5) + (quad << 3)];
#pragma unroll
    for (int n = 0; n < 8; n++) {
#pragma unroll
      for (int t = 0; t < 2; t++) {
        int sbi = ((t << 2) + quad) ^ (l16 & 7);
        bf16x8 av = *(const bf16x8*)&Vt[(((n << 4) + l16) << 6) + (sbi << 3)];
        acc_o[n] = __builtin_amdgcn_mfma_f32_16x16x32_bf16(av, bp[t], acc_o[n], 0, 0, 0);
      }
    }
  }

  // epilogue: O^T C-layout -> lane holds q=l16, dv = n*16+quad*4+r (8B stores)
  if (l16 == 0)
    *(float4*)&invlS[wave][quad << 2] =
        make_float4(1.f / l_i[0], 1.f / l_i[1], 1.f / l_i[2], 1.f / l_i[3]);
  asm volatile("s_waitcnt lgkmcnt(0)\n\ts_barrier" ::: "memory");
  float invl = invlS[wave][l16];
  int tok = (b << 10) + q0 + (wave << 4) + l16;
  bf16* obase = out + ((size_t)tok * HH + h) * DV + (quad << 2);
#pragma unroll
  for (int n = 0; n < 8; n++) {
    union { bf16 h4[4]; uint2 u; } pk;
#pragma unroll
    for (int r = 0; r < 4; r++) pk.h4[r] = (bf16)(acc_o[n][r] * invl);
    *(uint2*)(obase + (n << 4)) = pk.u;
  }
}

// ---------------- launch ----------------
extern "C" void kernel_launch(void* const* d_in, const int* in_sizes, int n_in,
                              void* d_out, int out_size, void* d_ws, size_t ws_size,
                              hipStream_t stream) {
  (void)in_sizes; (void)n_in; (void)out_size; (void)ws_size;
  const float* x        = (const float*)d_in[0];
  const float* wq_a     = (const float*)d_in[1];
  const float* w_qa_ln  = (const float*)d_in[2];
  const float* wq_b     = (const float*)d_in[3];
  const float* wkv_a    = (const float*)d_in[4];
  const float* w_kva_ln = (const float*)d_in[5];
  const float* wk_b     = (const float*)d_in[6];
  const float* wv_b     = (const float*)d_in[7];
  const float* wo       = (const float*)d_in[8];
  const float* rsin     = (const float*)d_in[9];
  const float* rcos     = (const float*)d_in[10];
  float* out = (float*)d_out;

  // workspace (liveness-aliased), total ~112.2 MB
  char* ws = (char*)d_ws;
  bf16* xb    = (bf16*)(ws + 0);            // 16.78M, dead after xout gemm
  bf16* attnb = (bf16*)(ws + 0);            //   aliases xb
  bf16* xout  = (bf16*)(ws + 16777216);     // 17.83M [4096][2176]
  bf16* knope = (bf16*)(ws + 16777216);     //   aliases xout, stride 2048
  bf16* q     = (bf16*)(ws + 34603008);     // 25.17M
  bf16* qln   = (bf16*)(ws + 59768832);     // 12.58M, dead after q gemm
  bf16* vT    = (bf16*)(ws + 59768832);     //   aliases qln
  bf16* wA    = (bf16*)(ws + 76546048);     // 8.91M  [2176][2048]
  bf16* wqbb  = (bf16*)(ws + 85458944);     // 9.44M
  bf16* wkvB  = (bf16*)(ws + 94896128);     // 4.19M  [4096][512]
  bf16* wob   = (bf16*)(ws + 99090432);     // 8.39M
  bf16* ckv   = (bf16*)(ws + 107479040);    // 4.19M
  bf16* kpe   = (bf16*)(ws + 111673344);    // 0.52M -> end 112197632

  const float SCALEQ = (1.0f / sqrtf(192.0f)) * 1.44269504088896f;

  dim3 blk(256);
  cvt_all<<<23296, blk, 0, stream>>>(x, wq_a, wkv_a, wq_b, wk_b, wv_b, wo,
                                     xb, wA, wqbb, wkvB, wob, SCALEQ);
  // xout = xb @ [wq_a ; wkv_a]^T
  gemm_bt_bf16<bf16, 0><<<dim3(32, 17), blk, 0, stream>>>(
      xb, wA, xout, nullptr, NTOK, XOUTW, HID);
  // rmsnorm(q), rmsnorm(kv), rope_k in one dispatch
  norm_rope<<<8704, blk, 0, stream>>>(xout, w_qa_ln, w_kva_ln, qln, ckv, kpe,
                                      rsin, rcos);
  // q = qln @ wq_b^T (pre-scaled by SCALEQ)
  gemm_bt_bf16<bf16, 0><<<dim3(32, 24), blk, 0, stream>>>(
      qln, wqbb, q, nullptr, NTOK, HH * DQK, QLR);
  rope_q<<<8192, blk, 0, stream>>>(q, rsin, rcos);
  // [knope | vT] = ckv @ [wk_b ; wv_b]^T (dual epilogue)
  gemm_bt_bf16<bf16, 1><<<dim3(32, 32), blk, 0, stream>>>(
      ckv, wkvB, knope, vT, NTOK, 4096, KVLR);
  attn_kernel<<<dim3(8, HH, BB), dim3(512), 0, stream>>>(
      q, knope, kpe, vT, attnb);
  gemm_bt_bf16<float, 0><<<dim3(32, 16), blk, 0, stream>>>(
      attnb, wob, out, nullptr, NTOK, HID, HID);
}